// Round 17
// baseline (775.748 us; speedup 1.0000x reference)
//
#include <hip/hip_runtime.h>
#include <math.h>

#define NROI 512
#define CDIM 256
#define TENC 32
#define TDEC 25
#define VOCC 97

typedef unsigned short ushort_t;
typedef unsigned char uchar_t;
typedef __attribute__((ext_vector_type(8))) short short8v;
typedef __attribute__((ext_vector_type(4))) float float4v;

// fast sigmoid/tanh: v_rcp instead of IEEE division (~1e-7 rel err)
__device__ __forceinline__ float sigmoidf_(float x){
    x = fminf(fmaxf(x, -30.f), 30.f);
    return __builtin_amdgcn_rcpf(1.f + __expf(-x));
}
__device__ __forceinline__ float tanhf_(float x){
    x = fminf(fmaxf(x, -15.f), 15.f);
    float e = __expf(2.f * x);
    return (e - 1.f) * __builtin_amdgcn_rcpf(e + 1.f);
}
__device__ __forceinline__ ushort_t f2b(float f){
    unsigned u = __float_as_uint(f);
    u = u + 0x7fffu + ((u >> 16) & 1u);
    return (ushort_t)(u >> 16);
}
__device__ __forceinline__ float b2f(ushort_t h){
    return __uint_as_float(((unsigned)h) << 16);
}
// float -> OCP fp8 e4m3 (RNE via HW cvt, clamped to +-448)
__device__ __forceinline__ uchar_t f2fp8(float x){
    x = fminf(fmaxf(x, -448.f), 448.f);
    int p = __builtin_amdgcn_cvt_pk_fp8_f32(x, x, 0, false);
    return (uchar_t)(p & 0xff);
}

// ---------------------------------------------------------------------------
// One-shot weight conversion / reorder (bf16 / fp8) + bias merges.
// ---------------------------------------------------------------------------
__global__ void convert_all_k(
    const float* c1s, const float* c2s, const float* wf, const float* wb,
    const float* hf, const float* hb, const float* em, const float* cb,
    const float* gi, const float* gh, const float* ow, const float* ob,
    const float* bif, const float* bhf, const float* bib, const float* bhb,
    ushort_t* d_c1, ushort_t* d_c2, ushort_t* d_wf, ushort_t* d_wb,
    uchar_t* d_hf8, uchar_t* d_hb8, ushort_t* d_em,
    ushort_t* d_cwL, uchar_t* d_cwR8,
    uchar_t* d_gi8, uchar_t* d_gh8, ushort_t* d_ow, float* d_ob,
    float* d_b2f, float* d_b2b)
{
    int i = blockIdx.x * 256 + threadIdx.x;
    if (i < 589824) {   // conv1 reorder [co][ci][9] -> [co][tap][ci]
        int co = i / 2304, rem = i % 2304, tap = rem >> 8, ci = rem & 255;
        d_c1[i] = f2b(c1s[co * 2304 + ci * 9 + tap]); return;
    }
    i -= 589824;
    if (i < 589824) {
        int co = i / 2304, rem = i % 2304, tap = rem >> 8, ci = rem & 255;
        d_c2[i] = f2b(c2s[co * 2304 + ci * 9 + tap]); return;
    }
    i -= 589824;
    if (i < 262144) { d_wf[i] = f2b(wf[i]); return; }  i -= 262144;
    if (i < 262144) { d_wb[i] = f2b(wb[i]); return; }  i -= 262144;
    if (i < 262144) { d_hf8[i] = f2fp8(hf[i]); return; }  i -= 262144;
    if (i < 262144) { d_hb8[i] = f2fp8(hb[i]); return; }  i -= 262144;
    if (i < 131072) { d_em[i] = f2b(em[i]); return; }  i -= 131072;
    if (i < 131072) {   // comb split
        int col = i >> 9, rest = i & 511;
        float v = cb[i];
        if (rest < 256) d_cwL[col * 256 + rest] = f2b(v);
        else            d_cwR8[col * 256 + (rest - 256)] = f2fp8(v);
        return;
    }
    i -= 131072;
    if (i < 196608) { d_gi8[i] = f2fp8(gi[i]); return; }  i -= 196608;
    if (i < 196608) { d_gh8[i] = f2fp8(gh[i]); return; }  i -= 196608;
    if (i < 32768) {    // out_w padded 97 -> 128 rows
        int r = i >> 8;
        d_ow[i] = (r < VOCC) ? f2b(ow[i - (r << 8) + r * 256]) : 0; return;
    }
    i -= 32768;
    if (i < 128) { d_ob[i] = (i < VOCC) ? ob[i] : 0.f; return; }  i -= 128;
    if (i < 1024) { d_b2f[i] = bif[i] + bhf[i]; return; }  i -= 1024;
    if (i < 1024) { d_b2b[i] = bib[i] + bhb[i]; return; }
}

// rois NCHW fp32 (512,256,8,32) -> R NHWC bf16 (512,8,32,256); LDS transpose
__global__ void nchw2nhwc_k(const float* __restrict__ in, ushort_t* __restrict__ out)
{
    __shared__ float t[64][33];
    int b = blockIdx.x;
    int cb = b & 3, h = (b >> 2) & 7, n = b >> 5;
    const float* src = in + (((size_t)n * 256 + cb * 64) * 8 + h) * 32;
    int w = threadIdx.x & 31, cr = threadIdx.x >> 5;
    #pragma unroll
    for (int p = 0; p < 8; p++) {
        int c = p * 8 + cr;
        t[c][w] = src[(size_t)c * 256 + w];
    }
    __syncthreads();
    int c2 = threadIdx.x & 63, wr2 = threadIdx.x >> 6;
    ushort_t* dst = out + ((size_t)n * 8 + h) * 32 * 256 + cb * 64;
    #pragma unroll
    for (int q = 0; q < 8; q++) {
        int ww = q * 4 + wr2;
        dst[(size_t)ww * 256 + c2] = f2b(t[c2][ww]);
    }
}

// teacher-forcing embedding gather: EMB (25,512,256) bf16
__global__ void emb_gather_k(const int* __restrict__ targets, const float* __restrict__ att_emb,
                             ushort_t* __restrict__ EMB)
{
    int idx = blockIdx.x * 256 + threadIdx.x;   // 3,276,800
    int c = idx & 255;
    int n = (idx >> 8) & 511;
    int t = idx >> 17;
    int tok = (t == 0) ? 0 : targets[n * TDEC + t - 1];
    EMB[idx] = f2b(att_emb[tok * 256 + c]);
}

// ---------------------------------------------------------------------------
// MFMA bf16 GEMM: C[M,N] = act(A[M,K]@B[N,K]^T + bias); 128x128 tile.
// ---------------------------------------------------------------------------
template<int OUTBF, int ACT>
__global__ void __launch_bounds__(256, 2)
mgemm_k(const ushort_t* __restrict__ A, const ushort_t* __restrict__ B,
        const float* __restrict__ bias, void* __restrict__ Cout,
        int M, int N, int K)
{
    __shared__ ushort_t As[128 * 40];
    __shared__ ushort_t Bs[128 * 40];
    const int tid = threadIdx.x;
    const int lane = tid & 63, wid = tid >> 6;
    const int wr = wid >> 1, wc = wid & 1;
    const int bm = blockIdx.y * 128, bn = blockIdx.x * 128;

    const int r0 = tid >> 2, c0 = tid & 3;
    const int r1 = r0 + 64;
    const size_t Ar0 = (size_t)(bm + r0) * K, Ar1 = (size_t)(bm + r1) * K;
    const size_t Br0 = (size_t)(bn + r0) * K, Br1 = (size_t)(bn + r1) * K;

    float4v acc[4][4];
    #pragma unroll
    for (int m = 0; m < 4; m++)
        #pragma unroll
        for (int n = 0; n < 4; n++) { float4v z = {0.f,0.f,0.f,0.f}; acc[m][n] = z; }

    short8v ra[2][2], rb[2][2];
    auto LOAD = [&](int b, int k0) {
        ra[b][0] = *(const short8v*)&A[Ar0 + k0 + c0 * 8];
        ra[b][1] = *(const short8v*)&A[Ar1 + k0 + c0 * 8];
        rb[b][0] = *(const short8v*)&B[Br0 + k0 + c0 * 8];
        rb[b][1] = *(const short8v*)&B[Br1 + k0 + c0 * 8];
    };
    auto STORE = [&](int b) {
        *(short8v*)&As[r0 * 40 + c0 * 8] = ra[b][0];
        *(short8v*)&As[r1 * 40 + c0 * 8] = ra[b][1];
        *(short8v*)&Bs[r0 * 40 + c0 * 8] = rb[b][0];
        *(short8v*)&Bs[r1 * 40 + c0 * 8] = rb[b][1];
    };
    const int lr = lane & 15, lk = lane >> 4;
    auto COMPUTE = [&]() {
        short8v af[4], bf[4];
        #pragma unroll
        for (int m = 0; m < 4; m++)
            af[m] = *(const short8v*)&As[(wr * 64 + m * 16 + lr) * 40 + lk * 8];
        #pragma unroll
        for (int n = 0; n < 4; n++)
            bf[n] = *(const short8v*)&Bs[(wc * 64 + n * 16 + lr) * 40 + lk * 8];
        #pragma unroll
        for (int m = 0; m < 4; m++)
            #pragma unroll
            for (int n = 0; n < 4; n++)
                acc[m][n] = __builtin_amdgcn_mfma_f32_16x16x32_bf16(af[m], bf[n], acc[m][n], 0, 0, 0);
    };

    LOAD(0, 0);
    for (int k0 = 0; k0 < K; k0 += 64) {
        __syncthreads();
        STORE(0);
        __syncthreads();
        LOAD(1, k0 + 32);
        COMPUTE();
        __syncthreads();
        STORE(1);
        __syncthreads();
        if (k0 + 64 < K) LOAD(0, k0 + 64);
        COMPUTE();
    }

    #pragma unroll
    for (int m = 0; m < 4; m++)
        #pragma unroll
        for (int n = 0; n < 4; n++)
            #pragma unroll
            for (int r = 0; r < 4; r++) {
                int row = bm + wr * 64 + m * 16 + lk * 4 + r;
                int col = bn + wc * 64 + n * 16 + lr;
                float v = acc[m][n][r];
                if (bias) v += bias[col];
                if (ACT == 1) v = fmaxf(v, 0.f);
                if (OUTBF) ((ushort_t*)Cout)[(size_t)row * N + col] = f2b(v);
                else       ((float*)   Cout)[(size_t)row * N + col] = v;
            }
}

// ---------------------------------------------------------------------------
// Conv 3x3 stride(2,1) pad(1,1), WIDE tile 128x256, FUSED GroupNorm+ReLU.
// ---------------------------------------------------------------------------
template<int CONV2>
__global__ void __launch_bounds__(256, 2)
convf_k(const ushort_t* __restrict__ in, const ushort_t* __restrict__ wt,
        const float* __restrict__ gns, const float* __restrict__ gnb,
        ushort_t* __restrict__ out, int Hin, int hmask, int nshift)
{
    const int K = 2304;
    __shared__ ushort_t As[128 * 40];
    __shared__ ushort_t Bs[256 * 40];
    const int tid = threadIdx.x;
    const int lane = tid & 63, wv = tid >> 6;
    const int byy = (blockIdx.y & 7) * (gridDim.y >> 3) + (blockIdx.y >> 3);
    const int bm = byy * 128;

    const int r0 = tid >> 2, c0 = tid & 3;
    const int r1 = r0 + 64;
    const int row0 = bm + r0, row1 = bm + r1;
    const int wo0 = row0 & 31, wo1 = row1 & 31;
    const int hh0 = ((row0 >> 5) & hmask) * 2 - 1, hh1 = ((row1 >> 5) & hmask) * 2 - 1;
    const size_t base0 = (size_t)(row0 >> nshift) * Hin * 32 * 256;
    const size_t base1 = (size_t)(row1 >> nshift) * Hin * 32 * 256;
    size_t Br[4];
    #pragma unroll
    for (int j = 0; j < 4; j++) Br[j] = (size_t)(r0 + j * 64) * K;

    float4v acc[8][4];
    #pragma unroll
    for (int m = 0; m < 8; m++)
        #pragma unroll
        for (int n = 0; n < 4; n++) { float4v z = {0.f,0.f,0.f,0.f}; acc[m][n] = z; }

    short8v ra[2][2], rb[2][4];
    const short8v zv = {0,0,0,0,0,0,0,0};
    auto LOAD = [&](int b, int k0) {
        int tap = k0 >> 8;
        int kh = tap / 3, kw = tap - kh * 3;
        int ci = (k0 & 255) + c0 * 8;
        int hi0 = hh0 + kh, wi0 = wo0 - 1 + kw;
        int hi1 = hh1 + kh, wi1 = wo1 - 1 + kw;
        ra[b][0] = ((unsigned)hi0 < (unsigned)Hin && (unsigned)wi0 < 32u)
                 ? *(const short8v*)&in[base0 + ((size_t)hi0 * 32 + wi0) * 256 + ci] : zv;
        ra[b][1] = ((unsigned)hi1 < (unsigned)Hin && (unsigned)wi1 < 32u)
                 ? *(const short8v*)&in[base1 + ((size_t)hi1 * 32 + wi1) * 256 + ci] : zv;
        #pragma unroll
        for (int j = 0; j < 4; j++)
            rb[b][j] = *(const short8v*)&wt[Br[j] + k0 + c0 * 8];
    };
    auto STORE = [&](int b) {
        *(short8v*)&As[r0 * 40 + c0 * 8] = ra[b][0];
        *(short8v*)&As[r1 * 40 + c0 * 8] = ra[b][1];
        #pragma unroll
        for (int j = 0; j < 4; j++)
            *(short8v*)&Bs[(r0 + j * 64) * 40 + c0 * 8] = rb[b][j];
    };
    const int lr = lane & 15, lk = lane >> 4;
    auto COMPUTE = [&]() {
        short8v af[8];
        #pragma unroll
        for (int m = 0; m < 8; m++)
            af[m] = *(const short8v*)&As[(m * 16 + lr) * 40 + lk * 8];
        #pragma unroll
        for (int n = 0; n < 4; n++) {
            short8v bf = *(const short8v*)&Bs[(wv * 64 + n * 16 + lr) * 40 + lk * 8];
            #pragma unroll
            for (int m = 0; m < 8; m++)
                acc[m][n] = __builtin_amdgcn_mfma_f32_16x16x32_bf16(af[m], bf, acc[m][n], 0, 0, 0);
        }
    };

    LOAD(0, 0);
    for (int k0 = 0; k0 < K; k0 += 64) {
        __syncthreads();
        STORE(0);
        __syncthreads();
        LOAD(1, k0 + 32);
        COMPUTE();
        __syncthreads();
        STORE(1);
        __syncthreads();
        if (k0 + 64 < K) LOAD(0, k0 + 64);
        COMPUTE();
    }

    // ---- fused GroupNorm epilogue (register stats, no LDS/barrier) ----
    float sc_[4], bb_[4];
    #pragma unroll
    for (int nn = 0; nn < 4; nn++) {
        int col = wv * 64 + nn * 16 + lr;
        sc_[nn] = gns[col];
        bb_[nn] = gnb[col];
    }

    if (CONV2 == 0) {
        float mu_[4], rs_[4];
        #pragma unroll
        for (int nn = 0; nn < 4; nn++) {
            float s = 0.f, q = 0.f;
            #pragma unroll
            for (int m = 0; m < 8; m++)
                #pragma unroll
                for (int r = 0; r < 4; r++) { float v = acc[m][nn][r]; s += v; q += v * v; }
            s += __shfl_xor(s, 16); q += __shfl_xor(q, 16);
            s += __shfl_xor(s, 32); q += __shfl_xor(q, 32);
            s += __shfl_xor(s, 1);  q += __shfl_xor(q, 1);
            s += __shfl_xor(s, 2);  q += __shfl_xor(q, 2);
            s += __shfl_xor(s, 4);  q += __shfl_xor(q, 4);
            float mu = s * (1.f / 1024.f);
            mu_[nn] = mu;
            rs_[nn] = rsqrtf(q * (1.f / 1024.f) - mu * mu + 1e-5f);
        }
        #pragma unroll
        for (int m = 0; m < 8; m++)
            #pragma unroll
            for (int nn = 0; nn < 4; nn++)
                #pragma unroll
                for (int r = 0; r < 4; r++) {
                    int row = bm + m * 16 + lk * 4 + r;
                    int col = wv * 64 + nn * 16 + lr;
                    float v = (acc[m][nn][r] - mu_[nn]) * rs_[nn] * sc_[nn] + bb_[nn];
                    out[(size_t)row * 256 + col] = f2b(fmaxf(v, 0.f));
                }
    } else {
        float mu_[2][4], rs_[2][4];
        #pragma unroll
        for (int img = 0; img < 2; img++)
            #pragma unroll
            for (int nn = 0; nn < 4; nn++) {
                float s = 0.f, q = 0.f;
                #pragma unroll
                for (int m2 = 0; m2 < 4; m2++)
                    #pragma unroll
                    for (int r = 0; r < 4; r++) {
                        float v = acc[img * 4 + m2][nn][r]; s += v; q += v * v;
                    }
                s += __shfl_xor(s, 16); q += __shfl_xor(q, 16);
                s += __shfl_xor(s, 32); q += __shfl_xor(q, 32);
                s += __shfl_xor(s, 1);  q += __shfl_xor(q, 1);
                s += __shfl_xor(s, 2);  q += __shfl_xor(q, 2);
                s += __shfl_xor(s, 4);  q += __shfl_xor(q, 4);
                float mu = s * (1.f / 512.f);
                mu_[img][nn] = mu;
                rs_[img][nn] = rsqrtf(q * (1.f / 512.f) - mu * mu + 1e-5f);
            }
        const int nimg0 = bm >> 6;
        #pragma unroll
        for (int img = 0; img < 2; img++)
            #pragma unroll
            for (int m2 = 0; m2 < 2; m2++)
                #pragma unroll
                for (int nn = 0; nn < 4; nn++)
                    #pragma unroll
                    for (int r = 0; r < 4; r++) {
                        int m = img * 4 + m2;
                        float v0 = (acc[m][nn][r]     - mu_[img][nn]) * rs_[img][nn] * sc_[nn] + bb_[nn];
                        float v1 = (acc[m + 2][nn][r] - mu_[img][nn]) * rs_[img][nn] * sc_[nn] + bb_[nn];
                        float pooled = 0.5f * (fmaxf(v0, 0.f) + fmaxf(v1, 0.f));
                        int wo = m2 * 16 + lk * 4 + r;
                        int nimg = nimg0 + img;
                        int col = wv * 64 + nn * 16 + lr;
                        out[((size_t)wo * 512 + nimg) * 256 + col] = f2b(pooled);
                    }
    }
}

// ---------------------------------------------------------------------------
// Persistent bidirectional LSTM v3: 256 blocks x 512 thr, 4 rois/block
// (4x CU coverage vs v2). Whh fp8 persistent in regs (128 VGPR); M=4.
// ---------------------------------------------------------------------------
__global__ void __launch_bounds__(512, 1)
lstm_persist_k(const ushort_t* __restrict__ XG,
               const uchar_t* __restrict__ whF8, const uchar_t* __restrict__ whB8,
               ushort_t* __restrict__ hcat)
{
    __shared__ __align__(16) uchar_t hf8[4][264];
    __shared__ float gL[4][1028];
    const int blk = blockIdx.x;          // 256 blocks
    const int dir = blk >> 7;
    const int r0  = (blk & 127) * 4;
    const uchar_t* W = dir ? whB8 : whF8;
    const int tid = threadIdx.x, lane = tid & 63, wv = tid >> 6;
    const int lr = lane & 15, lk = lane >> 4;
    const float4v z4 = {0.f, 0.f, 0.f, 0.f};

    long pw[8][8];
    #pragma unroll
    for (int j = 0; j < 8; j++) {
        int col0 = (j * 8 + wv) * 16;
        #pragma unroll
        for (int kf = 0; kf < 8; kf++)
            pw[j][kf] = *(const long*)&W[(size_t)(col0 + lr) * 256 + kf * 32 + lk * 8];
    }

    for (int i = tid; i < 4 * 264; i += 512) ((uchar_t*)hf8)[i] = 0;
    float creg[2];
    creg[0] = 0.f; creg[1] = 0.f;
    const int ccol = tid & 255;
    const int rbase = (tid >> 8) * 2;
    __syncthreads();

    for (int s = 0; s < TENC; s++) {
        int t = dir ? (31 - s) : s;
        float xga[8][4];
        if (lk == 0) {
            #pragma unroll
            for (int j = 0; j < 8; j++) {
                int col = (j * 8 + wv) * 16 + lr;
                #pragma unroll
                for (int r = 0; r < 4; r++)
                    xga[j][r] = b2f(XG[(size_t)t * 1048576 +
                                       (size_t)(r0 + r) * 2048 + dir * 1024 + col]);
            }
        }
        long aH[8];
        #pragma unroll
        for (int kf = 0; kf < 8; kf++)
            aH[kf] = (lr < 4) ? *(const long*)&hf8[lr][kf * 32 + lk * 8] : 0L;
        #pragma unroll
        for (int j = 0; j < 8; j++) {
            int col = (j * 8 + wv) * 16 + lr;
            float4v acc = z4;
            #pragma unroll
            for (int kf = 0; kf < 8; kf++)
                acc = __builtin_amdgcn_mfma_f32_16x16x32_fp8_fp8(aH[kf], pw[j][kf], acc, 0, 0, 0);
            if (lk == 0) {
                #pragma unroll
                for (int r = 0; r < 4; r++)
                    gL[r][col] = acc[r] + xga[j][r];
            }
        }
        __syncthreads();
        #pragma unroll
        for (int rr = 0; rr < 2; rr++) {
            int row = rbase + rr;
            float i_ = sigmoidf_(gL[row][ccol]);
            float f_ = sigmoidf_(gL[row][256 + ccol]);
            float g_ = tanhf_(gL[row][512 + ccol]);
            float o_ = sigmoidf_(gL[row][768 + ccol]);
            float cn = f_ * creg[rr] + i_ * g_;
            creg[rr] = cn;
            float hn = o_ * tanhf_(cn);
            hf8[row][ccol] = f2fp8(hn);
            hcat[((size_t)t * 512 + (r0 + row)) * 512 + dir * 256 + ccol] = f2b(hn);
        }
        __syncthreads();
    }
}

// ---------------------------------------------------------------------------
// Block-local attention-GRU decoder v10: 512 blocks x 512 thr, 1 roi/block.
// LDS ~57 KB -> 2 blocks/CU at 128 VGPR (16 waves/CU): co-resident blocks
// interleave barrier-bound phases. Same phase skeleton as v9 with M=1.
// ---------------------------------------------------------------------------
__global__ void __launch_bounds__(512, 4)
dec_local_k(const ushort_t* __restrict__ enc, const ushort_t* __restrict__ xinpre,
            const uchar_t* __restrict__ cwR8, const uchar_t* __restrict__ gwih8,
            const uchar_t* __restrict__ gwhh8, const float* __restrict__ gbih,
            const float* __restrict__ gbhh, const float* __restrict__ vw,
            const float* __restrict__ vb, ushort_t* __restrict__ hist)
{
    __shared__ ushort_t encL[32][264];
    __shared__ __align__(16) uchar_t cwL8[16 * 8 * 64 * 8];
    __shared__ float    hL[256];
    __shared__ __align__(16) uchar_t hf8[264];
    __shared__ __align__(16) uchar_t xf8[264];
    __shared__ __align__(16) uchar_t ctx8[264];
    __shared__ float    giL[776];
    __shared__ float    ghL[776];
    __shared__ float    scl[32];

    const int tid = threadIdx.x, lane = tid & 63, wv = tid >> 6;
    const int n = blockIdx.x;                 // 512 blocks, 1 roi each
    const int lr = lane & 15, lk = lane >> 4;
    const float4v z4 = {0.f,0.f,0.f,0.f};

    for (int i = tid; i < 256; i += 512) hL[i] = 0.f;
    for (int i = tid; i < 264; i += 512) hf8[i] = 0;
    // preload enc slice: 32 t2 x 256 ch
    for (int v = tid; v < 1024; v += 512) {
        int t2 = v >> 5;
        int c8 = (v & 31) * 8;
        *(short8v*)&encL[t2][c8] =
            *(const short8v*)&enc[((size_t)t2 * 512 + n) * 256 + c8];
    }
    // stage cwR8 in fragment order (wave wv owns tiles wv*2+q)
    #pragma unroll
    for (int q = 0; q < 2; q++) {
        int tile = wv * 2 + q;
        int col0 = tile * 16;
        #pragma unroll
        for (int kf = 0; kf < 8; kf++) {
            long v = *(const long*)&cwR8[(size_t)(col0 + lr) * 256 + kf * 32 + lk * 8];
            *(long*)&cwL8[((tile * 8 + kf) * 64 + lane) * 8] = v;
        }
    }
    long pgh[6][8], pgi[6][8];
    #pragma unroll
    for (int j = 0; j < 6; j++) {
        int col0 = (j * 8 + wv) * 16;
        #pragma unroll
        for (int kf = 0; kf < 8; kf++) {
            pgh[j][kf] = *(const long*)&gwhh8[(size_t)(col0 + lr) * 256 + kf * 32 + lk * 8];
            pgi[j][kf] = *(const long*)&gwih8[(size_t)(col0 + lr) * 256 + kf * 32 + lk * 8];
        }
    }
    __syncthreads();

    float vwreg[4];
    #pragma unroll
    for (int j = 0; j < 4; j++) vwreg[j] = vw[lane + 64 * j];
    const float vbias = vb[0];
    float gbh_r[6], gbi_r[6];
    #pragma unroll
    for (int j = 0; j < 6; j++) {
        int col0 = (j * 8 + wv) * 16;
        gbh_r[j] = gbhh[col0 + lr];
        gbi_r[j] = gbih[col0 + lr];
    }

    for (int t = 0; t < TDEC; t++) {
        // ---- step-start: prefetch xinpre ----
        float xp[2];
        #pragma unroll
        for (int q = 0; q < 2; q++) {
            int col0 = (wv * 2 + q) * 16;
            xp[q] = b2f(xinpre[(size_t)t * 131072 + (size_t)n * 256 + col0 + lr]);
        }
        // ---- gh MFMAs into regs (overlap with scores VALU) ----
        float4v ghacc[6];
        {
            long aH[8];
            #pragma unroll
            for (int kf = 0; kf < 8; kf++)
                aH[kf] = (lr == 0) ? *(const long*)&hf8[kf * 32 + lk * 8] : 0L;
            #pragma unroll
            for (int j = 0; j < 6; j++) {
                float4v acc = z4;
                #pragma unroll
                for (int kf = 0; kf < 8; kf++)
                    acc = __builtin_amdgcn_mfma_f32_16x16x32_fp8_fp8(aH[kf], pgh[j][kf], acc, 0, 0, 0);
                ghacc[j] = acc;
            }
        }
        // ---- attention scores: wave wv handles 4 t2 ----
        {
            int t2b = wv * 4;
            float hreg[4];
            #pragma unroll
            for (int j = 0; j < 4; j++) hreg[j] = hL[lane + 64 * j];
            #pragma unroll
            for (int q = 0; q < 4; q++) {
                int t2 = t2b + q;
                float s = 0.f;
                #pragma unroll
                for (int j = 0; j < 4; j++)
                    s += tanhf_(hreg[j] + b2f(encL[t2][lane + 64 * j])) * vwreg[j];
                for (int o = 32; o > 0; o >>= 1) s += __shfl_down(s, o);
                if (lane == 0) scl[t2] = s + vbias;
            }
        }
        // ---- write gh to LDS (row 0 only) ----
        if (lk == 0) {
            #pragma unroll
            for (int j = 0; j < 6; j++) {
                int col0 = (j * 8 + wv) * 16;
                ghL[col0 + lr] = ghacc[j][0] + gbh_r[j];
            }
        }
        __syncthreads();
        // ---- fused softmax + ctx (threads 0-255) ----
        if (tid < 256) {
            int c = tid;
            float m = -1e30f;
            #pragma unroll
            for (int t2 = 0; t2 < 32; t2++) m = fmaxf(m, scl[t2]);
            float ssum = 0.f, acc = 0.f;
            #pragma unroll 8
            for (int t2 = 0; t2 < 32; t2++) {
                float e = __expf(scl[t2] - m);
                ssum += e;
                acc += e * b2f(encL[t2][c]);
            }
            ctx8[c] = f2fp8(acc * __builtin_amdgcn_rcpf(ssum));
        }
        __syncthreads();
        // ---- xin = relu(xinpre + ctx @ cwR^T) -> fp8 ----
        {
            long aC[8];
            #pragma unroll
            for (int kf = 0; kf < 8; kf++)
                aC[kf] = (lr == 0) ? *(const long*)&ctx8[kf * 32 + lk * 8] : 0L;
            #pragma unroll
            for (int q = 0; q < 2; q++) {
                int tile = wv * 2 + q;
                int col0 = tile * 16;
                float4v acc = z4;
                #pragma unroll
                for (int kf = 0; kf < 8; kf++) {
                    long b = *(const long*)&cwL8[((tile * 8 + kf) * 64 + lane) * 8];
                    acc = __builtin_amdgcn_mfma_f32_16x16x32_fp8_fp8(aC[kf], b, acc, 0, 0, 0);
                }
                if (lk == 0)
                    xf8[col0 + lr] = f2fp8(fmaxf(acc[0] + xp[q], 0.f));
            }
        }
        __syncthreads();
        // ---- gi = xin @ gwih^T + gbih ----
        {
            long aX[8];
            #pragma unroll
            for (int kf = 0; kf < 8; kf++)
                aX[kf] = (lr == 0) ? *(const long*)&xf8[kf * 32 + lk * 8] : 0L;
            #pragma unroll
            for (int j = 0; j < 6; j++) {
                int col0 = (j * 8 + wv) * 16;
                float4v acc = z4;
                #pragma unroll
                for (int kf = 0; kf < 8; kf++)
                    acc = __builtin_amdgcn_mfma_f32_16x16x32_fp8_fp8(aX[kf], pgi[j][kf], acc, 0, 0, 0);
                if (lk == 0)
                    giL[col0 + lr] = acc[0] + gbi_r[j];
            }
        }
        __syncthreads();
        // ---- GRU cell (threads 0-255), non-temporal hist store ----
        if (tid < 256) {
            int c = tid;
            float rg = sigmoidf_(giL[c] + ghL[c]);
            float zg = sigmoidf_(giL[256 + c] + ghL[256 + c]);
            float ng = tanhf_(giL[512 + c] + rg * ghL[512 + c]);
            float hv = (1.f - zg) * ng + zg * hL[c];
            hL[c] = hv;
            hf8[c] = f2fp8(hv);
            __builtin_nontemporal_store(f2b(hv), &hist[((size_t)t * 512 + n) * 256 + c]);
        }
        __syncthreads();
    }
}

// per-step NLL means from padded logits (12800 x 128); block per t
__global__ void loss_batch_k(const float* __restrict__ logits, const int* __restrict__ targets,
                             float* __restrict__ part)
{
    __shared__ float red[256];
    int t = blockIdx.x;
    float acc = 0.f;
    for (int rr = threadIdx.x; rr < 512; rr += 256) {
        const float* row = logits + ((size_t)t * 512 + rr) * 128;
        float m = -1e30f;
        for (int j = 0; j < VOCC; j++) m = fmaxf(m, row[j]);
        float s2 = 0.f;
        for (int j = 0; j < VOCC; j++) s2 += __expf(row[j] - m);
        int tg = targets[rr * TDEC + t];
        acc += m + __logf(s2) - row[tg];
    }
    red[threadIdx.x] = acc;
    __syncthreads();
    for (int o = 128; o > 0; o >>= 1) {
        if (threadIdx.x < o) red[threadIdx.x] += red[threadIdx.x + o];
        __syncthreads();
    }
    if (threadIdx.x == 0) part[t] = red[0] / 512.f;
}

__global__ void loss_final_k(const float* __restrict__ part, float* __restrict__ out)
{
    if (threadIdx.x == 0) {
        float s = 0.f;
        for (int t = 0; t < TDEC; t++) s += part[t];
        out[0] = s;
    }
}

extern "C" void kernel_launch(void* const* d_in, const int* in_sizes, int n_in,
                              void* d_out, int out_size, void* d_ws, size_t ws_size,
                              hipStream_t stream)
{
    const float* rois     = (const float*)d_in[0];
    const int*   targets  = (const int*)  d_in[1];
    const float* conv1_w  = (const float*)d_in[2];
    const float* gn1_s    = (const float*)d_in[3];
    const float* gn1_b    = (const float*)d_in[4];
    const float* conv2_w  = (const float*)d_in[5];
    const float* gn2_s    = (const float*)d_in[6];
    const float* gn2_b    = (const float*)d_in[7];
    const float* wih_f    = (const float*)d_in[8];
    const float* whh_f    = (const float*)d_in[9];
    const float* bih_f    = (const float*)d_in[10];
    const float* bhh_f    = (const float*)d_in[11];
    const float* wih_b    = (const float*)d_in[12];
    const float* whh_b    = (const float*)d_in[13];
    const float* bih_b    = (const float*)d_in[14];
    const float* bhh_b    = (const float*)d_in[15];
    const float* emb_w    = (const float*)d_in[16];
    const float* emb_b    = (const float*)d_in[17];
    const float* att_emb  = (const float*)d_in[18];
    const float* comb_w   = (const float*)d_in[19];
    const float* comb_b   = (const float*)d_in[20];
    const float* gru_wih  = (const float*)d_in[21];
    const float* gru_whh  = (const float*)d_in[22];
    const float* gru_bih  = (const float*)d_in[23];
    const float* gru_bhh  = (const float*)d_in[24];
    const float* out_w    = (const float*)d_in[25];
    const float* out_b    = (const float*)d_in[26];
    const float* vat_w    = (const float*)d_in[27];
    const float* vat_b    = (const float*)d_in[28];

    float* ws = (float*)d_ws;
    const size_t REG1 = 0;              // R | xg (merged gates) | EMB+xinpre
    const size_t REG2 = 16777216;       // xT | hcat
    const size_t REG3 = 25165824;       // X1b | enc+hist+logitsA+lpart
    const size_t WREG = 33554432;

    ushort_t* R      = (ushort_t*)(ws + REG1);
    ushort_t* xg     = (ushort_t*)(ws + REG1);                 // (16384,2048) merged
    ushort_t* EMB    = (ushort_t*)(ws + REG1);                 // (25,512,256) bf16
    ushort_t* xinpre = (ushort_t*)(ws + REG1 + 1638400);       // (25,512,256) bf16

    ushort_t* xT     = (ushort_t*)(ws + REG2 + 4194304);       // (32,512,256)
    ushort_t* hcat   = (ushort_t*)(ws + REG2);                 // (16384,512)
    ushort_t* X1b    = (ushort_t*)(ws + REG3);                 // (65536,256)
    ushort_t* enc    = (ushort_t*)(ws + REG3);                 // (32,512,256) bf16
    ushort_t* hist   = (ushort_t*)(ws + REG3 + 2097152);       // (25,512,256) bf16
    float*    logitsA= ws + REG3 + 3735552;                    // (12800,128)
    float*    lpart  = ws + REG3 + 5373952;                    // 25

    ushort_t* c1w    = (ushort_t*)(ws + WREG);
    ushort_t* c2w    = (ushort_t*)(ws + WREG + 294912);
    ushort_t* wihf   = (ushort_t*)(ws + WREG + 589824);        // [wihf|wihb] stacked
    uchar_t*  whhf8  = (uchar_t*) (ws + WREG + 851968);        // 262144 B fp8
    uchar_t*  whhb8  = (uchar_t*) (ws + WREG + 917504);        // 262144 B fp8
    ushort_t* embw   = (ushort_t*)(ws + WREG + 1114112);
    ushort_t* cwL    = (ushort_t*)(ws + WREG + 1179648);
    uchar_t*  cwR8   = (uchar_t*) (ws + WREG + 1212416);       // 65536 B fp8
    uchar_t*  gwih8  = (uchar_t*) (ws + WREG + 1245184);       // 196608 B fp8
    uchar_t*  gwhh8  = (uchar_t*) (ws + WREG + 1294336);       // 196608 B fp8
    ushort_t* outw   = (ushort_t*)(ws + WREG + 1343488);
    float*    outb   = ws + WREG + 1359872;
    float*    bias2f = ws + WREG + 1360000;                    // [bias2f|bias2b] stacked
    float*    bias2b = ws + WREG + 1361024;

    dim3 blk(256);

    convert_all_k<<<11402, blk, 0, stream>>>(
        conv1_w, conv2_w, wih_f, wih_b, whh_f, whh_b, emb_w, comb_w,
        gru_wih, gru_whh, out_w, out_b, bih_f, bhh_f, bih_b, bhh_b,
        c1w, c2w, wihf, (ushort_t*)(ws + WREG + 720896), whhf8, whhb8, embw,
        cwL, cwR8, gwih8, gwhh8, outw, outb, bias2f, bias2b);

    // ---- encoder: conv1+GN1 fused, conv2+GN2+pool+transpose fused ----
    nchw2nhwc_k<<<16384, blk, 0, stream>>>(rois, R);
    convf_k<0><<<dim3(1, 512), blk, 0, stream>>>(R, c1w, gn1_s, gn1_b, X1b, 8, 3, 7);
    convf_k<1><<<dim3(1, 256), blk, 0, stream>>>(X1b, c2w, gn2_s, gn2_b, xT, 4, 1, 6);

    // ---- merged LSTM input gates: xg = xT @ [wihf;wihb]^T + [b2f;b2b] ----
    mgemm_k<1,0><<<dim3(16, 128), blk, 0, stream>>>(xT, wihf, bias2f, xg, 16384, 2048, 256);

    // ---- persistent bidirectional LSTM (256 blocks, fp8 weights in regs) ----
    lstm_persist_k<<<256, dim3(512), 0, stream>>>(xg, whhf8, whhb8, hcat);

    // enc = hcat @ emb_w^T + emb_b  (bf16 out)
    mgemm_k<1,0><<<dim3(2, 128), blk, 0, stream>>>(hcat, embw, emb_b, enc, 16384, 256, 512);

    // ---- decoder precompute: EMB gather + xinpre = EMB@cwL^T + comb_b (bf16) ----
    emb_gather_k<<<12800, blk, 0, stream>>>(targets, att_emb, EMB);
    mgemm_k<1,0><<<dim3(2, 100), blk, 0, stream>>>(EMB, cwL, comb_b, xinpre, 12800, 256, 256);

    // ---- block-local attention-GRU decoder (512 blocks x 1 roi, 2 blk/CU) ----
    dec_local_k<<<512, dim3(512), 0, stream>>>(enc, xinpre, cwR8, gwih8, gwhh8,
        gru_bih, gru_bhh, vat_w, vat_b, hist);

    // ---- deferred output projection + loss ----
    mgemm_k<0,0><<<dim3(1, 100), blk, 0, stream>>>(hist, outw, outb, logitsA, 12800, 128, 256);
    loss_batch_k<<<TDEC, blk, 0, stream>>>(logitsA, targets, lpart);
    loss_final_k<<<1, dim3(64), 0, stream>>>(lpart, (float*)d_out);
}

// Round 18
// 672.456 us; speedup vs baseline: 1.1536x; 1.1536x over previous
//
#include <hip/hip_runtime.h>
#include <math.h>

#define NROI 512
#define CDIM 256
#define TENC 32
#define TDEC 25
#define VOCC 97

typedef unsigned short ushort_t;
typedef unsigned char uchar_t;
typedef __attribute__((ext_vector_type(8))) short short8v;
typedef __attribute__((ext_vector_type(4))) float float4v;

// fast sigmoid/tanh: v_rcp instead of IEEE division (~1e-7 rel err)
__device__ __forceinline__ float sigmoidf_(float x){
    x = fminf(fmaxf(x, -30.f), 30.f);
    return __builtin_amdgcn_rcpf(1.f + __expf(-x));
}
__device__ __forceinline__ float tanhf_(float x){
    x = fminf(fmaxf(x, -15.f), 15.f);
    float e = __expf(2.f * x);
    return (e - 1.f) * __builtin_amdgcn_rcpf(e + 1.f);
}
__device__ __forceinline__ ushort_t f2b(float f){
    unsigned u = __float_as_uint(f);
    u = u + 0x7fffu + ((u >> 16) & 1u);
    return (ushort_t)(u >> 16);
}
__device__ __forceinline__ float b2f(ushort_t h){
    return __uint_as_float(((unsigned)h) << 16);
}
// float -> OCP fp8 e4m3 (RNE via HW cvt, clamped to +-448)
__device__ __forceinline__ uchar_t f2fp8(float x){
    x = fminf(fmaxf(x, -448.f), 448.f);
    int p = __builtin_amdgcn_cvt_pk_fp8_f32(x, x, 0, false);
    return (uchar_t)(p & 0xff);
}

// ---------------------------------------------------------------------------
// One-shot weight conversion / reorder (bf16 / fp8) + bias merges.
// ---------------------------------------------------------------------------
__global__ void convert_all_k(
    const float* c1s, const float* c2s, const float* wf, const float* wb,
    const float* hf, const float* hb, const float* em, const float* cb,
    const float* gi, const float* gh, const float* ow, const float* ob,
    const float* bif, const float* bhf, const float* bib, const float* bhb,
    ushort_t* d_c1, ushort_t* d_c2, ushort_t* d_wf, ushort_t* d_wb,
    uchar_t* d_hf8, uchar_t* d_hb8, ushort_t* d_em,
    ushort_t* d_cwL, uchar_t* d_cwR8,
    uchar_t* d_gi8, uchar_t* d_gh8, ushort_t* d_ow, float* d_ob,
    float* d_b2f, float* d_b2b)
{
    int i = blockIdx.x * 256 + threadIdx.x;
    if (i < 589824) {   // conv1 reorder [co][ci][9] -> [co][tap][ci]
        int co = i / 2304, rem = i % 2304, tap = rem >> 8, ci = rem & 255;
        d_c1[i] = f2b(c1s[co * 2304 + ci * 9 + tap]); return;
    }
    i -= 589824;
    if (i < 589824) {
        int co = i / 2304, rem = i % 2304, tap = rem >> 8, ci = rem & 255;
        d_c2[i] = f2b(c2s[co * 2304 + ci * 9 + tap]); return;
    }
    i -= 589824;
    if (i < 262144) { d_wf[i] = f2b(wf[i]); return; }  i -= 262144;
    if (i < 262144) { d_wb[i] = f2b(wb[i]); return; }  i -= 262144;
    if (i < 262144) { d_hf8[i] = f2fp8(hf[i]); return; }  i -= 262144;
    if (i < 262144) { d_hb8[i] = f2fp8(hb[i]); return; }  i -= 262144;
    if (i < 131072) { d_em[i] = f2b(em[i]); return; }  i -= 131072;
    if (i < 131072) {   // comb split
        int col = i >> 9, rest = i & 511;
        float v = cb[i];
        if (rest < 256) d_cwL[col * 256 + rest] = f2b(v);
        else            d_cwR8[col * 256 + (rest - 256)] = f2fp8(v);
        return;
    }
    i -= 131072;
    if (i < 196608) { d_gi8[i] = f2fp8(gi[i]); return; }  i -= 196608;
    if (i < 196608) { d_gh8[i] = f2fp8(gh[i]); return; }  i -= 196608;
    if (i < 32768) {    // out_w padded 97 -> 128 rows
        int r = i >> 8;
        d_ow[i] = (r < VOCC) ? f2b(ow[i - (r << 8) + r * 256]) : 0; return;
    }
    i -= 32768;
    if (i < 128) { d_ob[i] = (i < VOCC) ? ob[i] : 0.f; return; }  i -= 128;
    if (i < 1024) { d_b2f[i] = bif[i] + bhf[i]; return; }  i -= 1024;
    if (i < 1024) { d_b2b[i] = bib[i] + bhb[i]; return; }
}

// rois NCHW fp32 (512,256,8,32) -> R NHWC bf16 (512,8,32,256); LDS transpose
__global__ void nchw2nhwc_k(const float* __restrict__ in, ushort_t* __restrict__ out)
{
    __shared__ float t[64][33];
    int b = blockIdx.x;
    int cb = b & 3, h = (b >> 2) & 7, n = b >> 5;
    const float* src = in + (((size_t)n * 256 + cb * 64) * 8 + h) * 32;
    int w = threadIdx.x & 31, cr = threadIdx.x >> 5;
    #pragma unroll
    for (int p = 0; p < 8; p++) {
        int c = p * 8 + cr;
        t[c][w] = src[(size_t)c * 256 + w];
    }
    __syncthreads();
    int c2 = threadIdx.x & 63, wr2 = threadIdx.x >> 6;
    ushort_t* dst = out + ((size_t)n * 8 + h) * 32 * 256 + cb * 64;
    #pragma unroll
    for (int q = 0; q < 8; q++) {
        int ww = q * 4 + wr2;
        dst[(size_t)ww * 256 + c2] = f2b(t[c2][ww]);
    }
}

// teacher-forcing embedding gather: EMB (25,512,256) bf16
__global__ void emb_gather_k(const int* __restrict__ targets, const float* __restrict__ att_emb,
                             ushort_t* __restrict__ EMB)
{
    int idx = blockIdx.x * 256 + threadIdx.x;   // 3,276,800
    int c = idx & 255;
    int n = (idx >> 8) & 511;
    int t = idx >> 17;
    int tok = (t == 0) ? 0 : targets[n * TDEC + t - 1];
    EMB[idx] = f2b(att_emb[tok * 256 + c]);
}

// ---------------------------------------------------------------------------
// MFMA bf16 GEMM: C[M,N] = act(A[M,K]@B[N,K]^T + bias); 128x128 tile.
// ---------------------------------------------------------------------------
template<int OUTBF, int ACT>
__global__ void __launch_bounds__(256, 2)
mgemm_k(const ushort_t* __restrict__ A, const ushort_t* __restrict__ B,
        const float* __restrict__ bias, void* __restrict__ Cout,
        int M, int N, int K)
{
    __shared__ ushort_t As[128 * 40];
    __shared__ ushort_t Bs[128 * 40];
    const int tid = threadIdx.x;
    const int lane = tid & 63, wid = tid >> 6;
    const int wr = wid >> 1, wc = wid & 1;
    const int bm = blockIdx.y * 128, bn = blockIdx.x * 128;

    const int r0 = tid >> 2, c0 = tid & 3;
    const int r1 = r0 + 64;
    const size_t Ar0 = (size_t)(bm + r0) * K, Ar1 = (size_t)(bm + r1) * K;
    const size_t Br0 = (size_t)(bn + r0) * K, Br1 = (size_t)(bn + r1) * K;

    float4v acc[4][4];
    #pragma unroll
    for (int m = 0; m < 4; m++)
        #pragma unroll
        for (int n = 0; n < 4; n++) { float4v z = {0.f,0.f,0.f,0.f}; acc[m][n] = z; }

    short8v ra[2][2], rb[2][2];
    auto LOAD = [&](int b, int k0) {
        ra[b][0] = *(const short8v*)&A[Ar0 + k0 + c0 * 8];
        ra[b][1] = *(const short8v*)&A[Ar1 + k0 + c0 * 8];
        rb[b][0] = *(const short8v*)&B[Br0 + k0 + c0 * 8];
        rb[b][1] = *(const short8v*)&B[Br1 + k0 + c0 * 8];
    };
    auto STORE = [&](int b) {
        *(short8v*)&As[r0 * 40 + c0 * 8] = ra[b][0];
        *(short8v*)&As[r1 * 40 + c0 * 8] = ra[b][1];
        *(short8v*)&Bs[r0 * 40 + c0 * 8] = rb[b][0];
        *(short8v*)&Bs[r1 * 40 + c0 * 8] = rb[b][1];
    };
    const int lr = lane & 15, lk = lane >> 4;
    auto COMPUTE = [&]() {
        short8v af[4], bf[4];
        #pragma unroll
        for (int m = 0; m < 4; m++)
            af[m] = *(const short8v*)&As[(wr * 64 + m * 16 + lr) * 40 + lk * 8];
        #pragma unroll
        for (int n = 0; n < 4; n++)
            bf[n] = *(const short8v*)&Bs[(wc * 64 + n * 16 + lr) * 40 + lk * 8];
        #pragma unroll
        for (int m = 0; m < 4; m++)
            #pragma unroll
            for (int n = 0; n < 4; n++)
                acc[m][n] = __builtin_amdgcn_mfma_f32_16x16x32_bf16(af[m], bf[n], acc[m][n], 0, 0, 0);
    };

    LOAD(0, 0);
    for (int k0 = 0; k0 < K; k0 += 64) {
        __syncthreads();
        STORE(0);
        __syncthreads();
        LOAD(1, k0 + 32);
        COMPUTE();
        __syncthreads();
        STORE(1);
        __syncthreads();
        if (k0 + 64 < K) LOAD(0, k0 + 64);
        COMPUTE();
    }

    #pragma unroll
    for (int m = 0; m < 4; m++)
        #pragma unroll
        for (int n = 0; n < 4; n++)
            #pragma unroll
            for (int r = 0; r < 4; r++) {
                int row = bm + wr * 64 + m * 16 + lk * 4 + r;
                int col = bn + wc * 64 + n * 16 + lr;
                float v = acc[m][n][r];
                if (bias) v += bias[col];
                if (ACT == 1) v = fmaxf(v, 0.f);
                if (OUTBF) ((ushort_t*)Cout)[(size_t)row * N + col] = f2b(v);
                else       ((float*)   Cout)[(size_t)row * N + col] = v;
            }
}

// ---------------------------------------------------------------------------
// Conv 3x3 stride(2,1) pad(1,1), WIDE tile 128x256, FUSED GroupNorm+ReLU.
// ---------------------------------------------------------------------------
template<int CONV2>
__global__ void __launch_bounds__(256, 2)
convf_k(const ushort_t* __restrict__ in, const ushort_t* __restrict__ wt,
        const float* __restrict__ gns, const float* __restrict__ gnb,
        ushort_t* __restrict__ out, int Hin, int hmask, int nshift)
{
    const int K = 2304;
    __shared__ ushort_t As[128 * 40];
    __shared__ ushort_t Bs[256 * 40];
    const int tid = threadIdx.x;
    const int lane = tid & 63, wv = tid >> 6;
    const int byy = (blockIdx.y & 7) * (gridDim.y >> 3) + (blockIdx.y >> 3);
    const int bm = byy * 128;

    const int r0 = tid >> 2, c0 = tid & 3;
    const int r1 = r0 + 64;
    const int row0 = bm + r0, row1 = bm + r1;
    const int wo0 = row0 & 31, wo1 = row1 & 31;
    const int hh0 = ((row0 >> 5) & hmask) * 2 - 1, hh1 = ((row1 >> 5) & hmask) * 2 - 1;
    const size_t base0 = (size_t)(row0 >> nshift) * Hin * 32 * 256;
    const size_t base1 = (size_t)(row1 >> nshift) * Hin * 32 * 256;
    size_t Br[4];
    #pragma unroll
    for (int j = 0; j < 4; j++) Br[j] = (size_t)(r0 + j * 64) * K;

    float4v acc[8][4];
    #pragma unroll
    for (int m = 0; m < 8; m++)
        #pragma unroll
        for (int n = 0; n < 4; n++) { float4v z = {0.f,0.f,0.f,0.f}; acc[m][n] = z; }

    short8v ra[2][2], rb[2][4];
    const short8v zv = {0,0,0,0,0,0,0,0};
    auto LOAD = [&](int b, int k0) {
        int tap = k0 >> 8;
        int kh = tap / 3, kw = tap - kh * 3;
        int ci = (k0 & 255) + c0 * 8;
        int hi0 = hh0 + kh, wi0 = wo0 - 1 + kw;
        int hi1 = hh1 + kh, wi1 = wo1 - 1 + kw;
        ra[b][0] = ((unsigned)hi0 < (unsigned)Hin && (unsigned)wi0 < 32u)
                 ? *(const short8v*)&in[base0 + ((size_t)hi0 * 32 + wi0) * 256 + ci] : zv;
        ra[b][1] = ((unsigned)hi1 < (unsigned)Hin && (unsigned)wi1 < 32u)
                 ? *(const short8v*)&in[base1 + ((size_t)hi1 * 32 + wi1) * 256 + ci] : zv;
        #pragma unroll
        for (int j = 0; j < 4; j++)
            rb[b][j] = *(const short8v*)&wt[Br[j] + k0 + c0 * 8];
    };
    auto STORE = [&](int b) {
        *(short8v*)&As[r0 * 40 + c0 * 8] = ra[b][0];
        *(short8v*)&As[r1 * 40 + c0 * 8] = ra[b][1];
        #pragma unroll
        for (int j = 0; j < 4; j++)
            *(short8v*)&Bs[(r0 + j * 64) * 40 + c0 * 8] = rb[b][j];
    };
    const int lr = lane & 15, lk = lane >> 4;
    auto COMPUTE = [&]() {
        short8v af[8];
        #pragma unroll
        for (int m = 0; m < 8; m++)
            af[m] = *(const short8v*)&As[(m * 16 + lr) * 40 + lk * 8];
        #pragma unroll
        for (int n = 0; n < 4; n++) {
            short8v bf = *(const short8v*)&Bs[(wv * 64 + n * 16 + lr) * 40 + lk * 8];
            #pragma unroll
            for (int m = 0; m < 8; m++)
                acc[m][n] = __builtin_amdgcn_mfma_f32_16x16x32_bf16(af[m], bf, acc[m][n], 0, 0, 0);
        }
    };

    LOAD(0, 0);
    for (int k0 = 0; k0 < K; k0 += 64) {
        __syncthreads();
        STORE(0);
        __syncthreads();
        LOAD(1, k0 + 32);
        COMPUTE();
        __syncthreads();
        STORE(1);
        __syncthreads();
        if (k0 + 64 < K) LOAD(0, k0 + 64);
        COMPUTE();
    }

    // ---- fused GroupNorm epilogue (register stats, no LDS/barrier) ----
    float sc_[4], bb_[4];
    #pragma unroll
    for (int nn = 0; nn < 4; nn++) {
        int col = wv * 64 + nn * 16 + lr;
        sc_[nn] = gns[col];
        bb_[nn] = gnb[col];
    }

    if (CONV2 == 0) {
        float mu_[4], rs_[4];
        #pragma unroll
        for (int nn = 0; nn < 4; nn++) {
            float s = 0.f, q = 0.f;
            #pragma unroll
            for (int m = 0; m < 8; m++)
                #pragma unroll
                for (int r = 0; r < 4; r++) { float v = acc[m][nn][r]; s += v; q += v * v; }
            s += __shfl_xor(s, 16); q += __shfl_xor(q, 16);
            s += __shfl_xor(s, 32); q += __shfl_xor(q, 32);
            s += __shfl_xor(s, 1);  q += __shfl_xor(q, 1);
            s += __shfl_xor(s, 2);  q += __shfl_xor(q, 2);
            s += __shfl_xor(s, 4);  q += __shfl_xor(q, 4);
            float mu = s * (1.f / 1024.f);
            mu_[nn] = mu;
            rs_[nn] = rsqrtf(q * (1.f / 1024.f) - mu * mu + 1e-5f);
        }
        #pragma unroll
        for (int m = 0; m < 8; m++)
            #pragma unroll
            for (int nn = 0; nn < 4; nn++)
                #pragma unroll
                for (int r = 0; r < 4; r++) {
                    int row = bm + m * 16 + lk * 4 + r;
                    int col = wv * 64 + nn * 16 + lr;
                    float v = (acc[m][nn][r] - mu_[nn]) * rs_[nn] * sc_[nn] + bb_[nn];
                    out[(size_t)row * 256 + col] = f2b(fmaxf(v, 0.f));
                }
    } else {
        float mu_[2][4], rs_[2][4];
        #pragma unroll
        for (int img = 0; img < 2; img++)
            #pragma unroll
            for (int nn = 0; nn < 4; nn++) {
                float s = 0.f, q = 0.f;
                #pragma unroll
                for (int m2 = 0; m2 < 4; m2++)
                    #pragma unroll
                    for (int r = 0; r < 4; r++) {
                        float v = acc[img * 4 + m2][nn][r]; s += v; q += v * v;
                    }
                s += __shfl_xor(s, 16); q += __shfl_xor(q, 16);
                s += __shfl_xor(s, 32); q += __shfl_xor(q, 32);
                s += __shfl_xor(s, 1);  q += __shfl_xor(q, 1);
                s += __shfl_xor(s, 2);  q += __shfl_xor(q, 2);
                s += __shfl_xor(s, 4);  q += __shfl_xor(q, 4);
                float mu = s * (1.f / 512.f);
                mu_[img][nn] = mu;
                rs_[img][nn] = rsqrtf(q * (1.f / 512.f) - mu * mu + 1e-5f);
            }
        const int nimg0 = bm >> 6;
        #pragma unroll
        for (int img = 0; img < 2; img++)
            #pragma unroll
            for (int m2 = 0; m2 < 2; m2++)
                #pragma unroll
                for (int nn = 0; nn < 4; nn++)
                    #pragma unroll
                    for (int r = 0; r < 4; r++) {
                        int m = img * 4 + m2;
                        float v0 = (acc[m][nn][r]     - mu_[img][nn]) * rs_[img][nn] * sc_[nn] + bb_[nn];
                        float v1 = (acc[m + 2][nn][r] - mu_[img][nn]) * rs_[img][nn] * sc_[nn] + bb_[nn];
                        float pooled = 0.5f * (fmaxf(v0, 0.f) + fmaxf(v1, 0.f));
                        int wo = m2 * 16 + lk * 4 + r;
                        int nimg = nimg0 + img;
                        int col = wv * 64 + nn * 16 + lr;
                        out[((size_t)wo * 512 + nimg) * 256 + col] = f2b(pooled);
                    }
    }
}

// ---------------------------------------------------------------------------
// Persistent bidirectional LSTM v3: 256 blocks x 512 thr, 4 rois/block.
// ---------------------------------------------------------------------------
__global__ void __launch_bounds__(512, 1)
lstm_persist_k(const ushort_t* __restrict__ XG,
               const uchar_t* __restrict__ whF8, const uchar_t* __restrict__ whB8,
               ushort_t* __restrict__ hcat)
{
    __shared__ __align__(16) uchar_t hf8[4][264];
    __shared__ float gL[4][1028];
    const int blk = blockIdx.x;          // 256 blocks
    const int dir = blk >> 7;
    const int r0  = (blk & 127) * 4;
    const uchar_t* W = dir ? whB8 : whF8;
    const int tid = threadIdx.x, lane = tid & 63, wv = tid >> 6;
    const int lr = lane & 15, lk = lane >> 4;
    const float4v z4 = {0.f, 0.f, 0.f, 0.f};

    long pw[8][8];
    #pragma unroll
    for (int j = 0; j < 8; j++) {
        int col0 = (j * 8 + wv) * 16;
        #pragma unroll
        for (int kf = 0; kf < 8; kf++)
            pw[j][kf] = *(const long*)&W[(size_t)(col0 + lr) * 256 + kf * 32 + lk * 8];
    }

    for (int i = tid; i < 4 * 264; i += 512) ((uchar_t*)hf8)[i] = 0;
    float creg[2];
    creg[0] = 0.f; creg[1] = 0.f;
    const int ccol = tid & 255;
    const int rbase = (tid >> 8) * 2;
    __syncthreads();

    for (int s = 0; s < TENC; s++) {
        int t = dir ? (31 - s) : s;
        float xga[8][4];
        if (lk == 0) {
            #pragma unroll
            for (int j = 0; j < 8; j++) {
                int col = (j * 8 + wv) * 16 + lr;
                #pragma unroll
                for (int r = 0; r < 4; r++)
                    xga[j][r] = b2f(XG[(size_t)t * 1048576 +
                                       (size_t)(r0 + r) * 2048 + dir * 1024 + col]);
            }
        }
        long aH[8];
        #pragma unroll
        for (int kf = 0; kf < 8; kf++)
            aH[kf] = (lr < 4) ? *(const long*)&hf8[lr][kf * 32 + lk * 8] : 0L;
        #pragma unroll
        for (int j = 0; j < 8; j++) {
            int col = (j * 8 + wv) * 16 + lr;
            float4v acc = z4;
            #pragma unroll
            for (int kf = 0; kf < 8; kf++)
                acc = __builtin_amdgcn_mfma_f32_16x16x32_fp8_fp8(aH[kf], pw[j][kf], acc, 0, 0, 0);
            if (lk == 0) {
                #pragma unroll
                for (int r = 0; r < 4; r++)
                    gL[r][col] = acc[r] + xga[j][r];
            }
        }
        __syncthreads();
        #pragma unroll
        for (int rr = 0; rr < 2; rr++) {
            int row = rbase + rr;
            float i_ = sigmoidf_(gL[row][ccol]);
            float f_ = sigmoidf_(gL[row][256 + ccol]);
            float g_ = tanhf_(gL[row][512 + ccol]);
            float o_ = sigmoidf_(gL[row][768 + ccol]);
            float cn = f_ * creg[rr] + i_ * g_;
            creg[rr] = cn;
            float hn = o_ * tanhf_(cn);
            hf8[row][ccol] = f2fp8(hn);
            hcat[((size_t)t * 512 + (r0 + row)) * 512 + dir * 256 + ccol] = f2b(hn);
        }
        __syncthreads();
    }
}

// ---------------------------------------------------------------------------
// Block-local attention-GRU decoder v9 (proven round-15/16 version):
// 256 blocks x 512 thr, 2 rois/block, persistent fp8 weights, fast
// transcendentals, fused softmax+ctx, gh hoisted, xinpre prefetch.
// ---------------------------------------------------------------------------
__global__ void __launch_bounds__(512, 1)
dec_local_k(const ushort_t* __restrict__ enc, const ushort_t* __restrict__ xinpre,
            const uchar_t* __restrict__ cwR8, const uchar_t* __restrict__ gwih8,
            const uchar_t* __restrict__ gwhh8, const float* __restrict__ gbih,
            const float* __restrict__ gbhh, const float* __restrict__ vw,
            const float* __restrict__ vb, ushort_t* __restrict__ hist)
{
    __shared__ ushort_t encL[2][32][264];
    __shared__ __align__(16) uchar_t cwL8[16 * 8 * 64 * 8];
    __shared__ float    hL[2][256];
    __shared__ __align__(16) uchar_t hf8[2][264];
    __shared__ __align__(16) uchar_t xf8[2][264];
    __shared__ __align__(16) uchar_t ctx8[2][264];
    __shared__ float    giL[2][776];
    __shared__ float    ghL[2][776];
    __shared__ float    scl[2][32];

    const int tid = threadIdx.x, lane = tid & 63, wv = tid >> 6;
    const int nbase = blockIdx.x * 2;
    const int lr = lane & 15, lk = lane >> 4;
    const float4v z4 = {0.f,0.f,0.f,0.f};

    for (int i = tid; i < 2 * 256; i += 512) hL[i >> 8][i & 255] = 0.f;
    for (int i = tid; i < 2 * 264; i += 512) hf8[i / 264][i % 264] = 0;
    for (int v = tid; v < 2048; v += 512) {
        int r = v >> 10;
        int rem = v & 1023;
        int t2 = rem >> 5;
        int c8 = (rem & 31) * 8;
        *(short8v*)&encL[r][t2][c8] =
            *(const short8v*)&enc[((size_t)t2 * 512 + nbase + r) * 256 + c8];
    }
    #pragma unroll
    for (int q = 0; q < 2; q++) {
        int tile = wv * 2 + q;
        int col0 = tile * 16;
        #pragma unroll
        for (int kf = 0; kf < 8; kf++) {
            long v = *(const long*)&cwR8[(size_t)(col0 + lr) * 256 + kf * 32 + lk * 8];
            *(long*)&cwL8[((tile * 8 + kf) * 64 + lane) * 8] = v;
        }
    }
    long pgh[6][8], pgi[6][8];
    #pragma unroll
    for (int j = 0; j < 6; j++) {
        int col0 = (j * 8 + wv) * 16;
        #pragma unroll
        for (int kf = 0; kf < 8; kf++) {
            pgh[j][kf] = *(const long*)&gwhh8[(size_t)(col0 + lr) * 256 + kf * 32 + lk * 8];
            pgi[j][kf] = *(const long*)&gwih8[(size_t)(col0 + lr) * 256 + kf * 32 + lk * 8];
        }
    }
    __syncthreads();

    float vwreg[4];
    #pragma unroll
    for (int j = 0; j < 4; j++) vwreg[j] = vw[lane + 64 * j];
    const float vbias = vb[0];
    float gbh_r[6], gbi_r[6];
    #pragma unroll
    for (int j = 0; j < 6; j++) {
        int col0 = (j * 8 + wv) * 16;
        gbh_r[j] = gbhh[col0 + lr];
        gbi_r[j] = gbih[col0 + lr];
    }

    for (int t = 0; t < TDEC; t++) {
        float xp[2][2];
        #pragma unroll
        for (int q = 0; q < 2; q++) {
            int col0 = (wv * 2 + q) * 16;
            xp[q][0] = b2f(xinpre[(size_t)t * 131072 + (size_t)(nbase + 0) * 256 + col0 + lr]);
            xp[q][1] = b2f(xinpre[(size_t)t * 131072 + (size_t)(nbase + 1) * 256 + col0 + lr]);
        }
        float4v ghacc[6];
        {
            long aH[8];
            #pragma unroll
            for (int kf = 0; kf < 8; kf++)
                aH[kf] = (lr < 2) ? *(const long*)&hf8[lr][kf * 32 + lk * 8] : 0L;
            #pragma unroll
            for (int j = 0; j < 6; j++) {
                float4v acc = z4;
                #pragma unroll
                for (int kf = 0; kf < 8; kf++)
                    acc = __builtin_amdgcn_mfma_f32_16x16x32_fp8_fp8(aH[kf], pgh[j][kf], acc, 0, 0, 0);
                ghacc[j] = acc;
            }
        }
        {
            int r = wv >> 2;
            int t2b = (wv & 3) * 8;
            float hreg[4];
            #pragma unroll
            for (int j = 0; j < 4; j++) hreg[j] = hL[r][lane + 64 * j];
            #pragma unroll
            for (int q = 0; q < 8; q++) {
                int t2 = t2b + q;
                float s = 0.f;
                #pragma unroll
                for (int j = 0; j < 4; j++)
                    s += tanhf_(hreg[j] + b2f(encL[r][t2][lane + 64 * j])) * vwreg[j];
                for (int o = 32; o > 0; o >>= 1) s += __shfl_down(s, o);
                if (lane == 0) scl[r][t2] = s + vbias;
            }
        }
        if (lk == 0) {
            #pragma unroll
            for (int j = 0; j < 6; j++) {
                int col0 = (j * 8 + wv) * 16;
                ghL[0][col0 + lr] = ghacc[j][0] + gbh_r[j];
                ghL[1][col0 + lr] = ghacc[j][1] + gbh_r[j];
            }
        }
        __syncthreads();
        {
            int r = tid >> 8, c = tid & 255;
            float m = -1e30f;
            #pragma unroll
            for (int t2 = 0; t2 < 32; t2++) m = fmaxf(m, scl[r][t2]);
            float ssum = 0.f, acc = 0.f;
            #pragma unroll 8
            for (int t2 = 0; t2 < 32; t2++) {
                float e = __expf(scl[r][t2] - m);
                ssum += e;
                acc += e * b2f(encL[r][t2][c]);
            }
            ctx8[r][c] = f2fp8(acc * __builtin_amdgcn_rcpf(ssum));
        }
        __syncthreads();
        {
            long aC[8];
            #pragma unroll
            for (int kf = 0; kf < 8; kf++)
                aC[kf] = (lr < 2) ? *(const long*)&ctx8[lr][kf * 32 + lk * 8] : 0L;
            #pragma unroll
            for (int q = 0; q < 2; q++) {
                int tile = wv * 2 + q;
                int col0 = tile * 16;
                float4v acc = z4;
                #pragma unroll
                for (int kf = 0; kf < 8; kf++) {
                    long b = *(const long*)&cwL8[((tile * 8 + kf) * 64 + lane) * 8];
                    acc = __builtin_amdgcn_mfma_f32_16x16x32_fp8_fp8(aC[kf], b, acc, 0, 0, 0);
                }
                if (lk == 0) {
                    xf8[0][col0 + lr] = f2fp8(fmaxf(acc[0] + xp[q][0], 0.f));
                    xf8[1][col0 + lr] = f2fp8(fmaxf(acc[1] + xp[q][1], 0.f));
                }
            }
        }
        __syncthreads();
        {
            long aX[8];
            #pragma unroll
            for (int kf = 0; kf < 8; kf++)
                aX[kf] = (lr < 2) ? *(const long*)&xf8[lr][kf * 32 + lk * 8] : 0L;
            #pragma unroll
            for (int j = 0; j < 6; j++) {
                int col0 = (j * 8 + wv) * 16;
                float4v acc = z4;
                #pragma unroll
                for (int kf = 0; kf < 8; kf++)
                    acc = __builtin_amdgcn_mfma_f32_16x16x32_fp8_fp8(aX[kf], pgi[j][kf], acc, 0, 0, 0);
                if (lk == 0) {
                    giL[0][col0 + lr] = acc[0] + gbi_r[j];
                    giL[1][col0 + lr] = acc[1] + gbi_r[j];
                }
            }
        }
        __syncthreads();
        {
            int r = tid >> 8, c = tid & 255;
            float rg = sigmoidf_(giL[r][c] + ghL[r][c]);
            float zg = sigmoidf_(giL[r][256 + c] + ghL[r][256 + c]);
            float ng = tanhf_(giL[r][512 + c] + rg * ghL[r][512 + c]);
            float hv = (1.f - zg) * ng + zg * hL[r][c];
            hL[r][c] = hv;
            hf8[r][c] = f2fp8(hv);
            __builtin_nontemporal_store(f2b(hv), &hist[((size_t)t * 512 + nbase + r) * 256 + c]);
        }
        __syncthreads();
    }
}

// per-step NLL means from padded logits (12800 x 128); block per t
__global__ void loss_batch_k(const float* __restrict__ logits, const int* __restrict__ targets,
                             float* __restrict__ part)
{
    __shared__ float red[256];
    int t = blockIdx.x;
    float acc = 0.f;
    for (int rr = threadIdx.x; rr < 512; rr += 256) {
        const float* row = logits + ((size_t)t * 512 + rr) * 128;
        float m = -1e30f;
        for (int j = 0; j < VOCC; j++) m = fmaxf(m, row[j]);
        float s2 = 0.f;
        for (int j = 0; j < VOCC; j++) s2 += __expf(row[j] - m);
        int tg = targets[rr * TDEC + t];
        acc += m + __logf(s2) - row[tg];
    }
    red[threadIdx.x] = acc;
    __syncthreads();
    for (int o = 128; o > 0; o >>= 1) {
        if (threadIdx.x < o) red[threadIdx.x] += red[threadIdx.x + o];
        __syncthreads();
    }
    if (threadIdx.x == 0) part[t] = red[0] / 512.f;
}

__global__ void loss_final_k(const float* __restrict__ part, float* __restrict__ out)
{
    if (threadIdx.x == 0) {
        float s = 0.f;
        for (int t = 0; t < TDEC; t++) s += part[t];
        out[0] = s;
    }
}

extern "C" void kernel_launch(void* const* d_in, const int* in_sizes, int n_in,
                              void* d_out, int out_size, void* d_ws, size_t ws_size,
                              hipStream_t stream)
{
    const float* rois     = (const float*)d_in[0];
    const int*   targets  = (const int*)  d_in[1];
    const float* conv1_w  = (const float*)d_in[2];
    const float* gn1_s    = (const float*)d_in[3];
    const float* gn1_b    = (const float*)d_in[4];
    const float* conv2_w  = (const float*)d_in[5];
    const float* gn2_s    = (const float*)d_in[6];
    const float* gn2_b    = (const float*)d_in[7];
    const float* wih_f    = (const float*)d_in[8];
    const float* whh_f    = (const float*)d_in[9];
    const float* bih_f    = (const float*)d_in[10];
    const float* bhh_f    = (const float*)d_in[11];
    const float* wih_b    = (const float*)d_in[12];
    const float* whh_b    = (const float*)d_in[13];
    const float* bih_b    = (const float*)d_in[14];
    const float* bhh_b    = (const float*)d_in[15];
    const float* emb_w    = (const float*)d_in[16];
    const float* emb_b    = (const float*)d_in[17];
    const float* att_emb  = (const float*)d_in[18];
    const float* comb_w   = (const float*)d_in[19];
    const float* comb_b   = (const float*)d_in[20];
    const float* gru_wih  = (const float*)d_in[21];
    const float* gru_whh  = (const float*)d_in[22];
    const float* gru_bih  = (const float*)d_in[23];
    const float* gru_bhh  = (const float*)d_in[24];
    const float* out_w    = (const float*)d_in[25];
    const float* out_b    = (const float*)d_in[26];
    const float* vat_w    = (const float*)d_in[27];
    const float* vat_b    = (const float*)d_in[28];

    float* ws = (float*)d_ws;
    const size_t REG1 = 0;              // R | xg (merged gates) | EMB+xinpre
    const size_t REG2 = 16777216;       // xT | hcat
    const size_t REG3 = 25165824;       // X1b | enc+hist+logitsA+lpart
    const size_t WREG = 33554432;

    ushort_t* R      = (ushort_t*)(ws + REG1);
    ushort_t* xg     = (ushort_t*)(ws + REG1);                 // (16384,2048) merged
    ushort_t* EMB    = (ushort_t*)(ws + REG1);                 // (25,512,256) bf16
    ushort_t* xinpre = (ushort_t*)(ws + REG1 + 1638400);       // (25,512,256) bf16

    ushort_t* xT     = (ushort_t*)(ws + REG2 + 4194304);       // (32,512,256)
    ushort_t* hcat   = (ushort_t*)(ws + REG2);                 // (16384,512)
    ushort_t* X1b    = (ushort_t*)(ws + REG3);                 // (65536,256)
    ushort_t* enc    = (ushort_t*)(ws + REG3);                 // (32,512,256) bf16
    ushort_t* hist   = (ushort_t*)(ws + REG3 + 2097152);       // (25,512,256) bf16
    float*    logitsA= ws + REG3 + 3735552;                    // (12800,128)
    float*    lpart  = ws + REG3 + 5373952;                    // 25

    ushort_t* c1w    = (ushort_t*)(ws + WREG);
    ushort_t* c2w    = (ushort_t*)(ws + WREG + 294912);
    ushort_t* wihf   = (ushort_t*)(ws + WREG + 589824);        // [wihf|wihb] stacked
    uchar_t*  whhf8  = (uchar_t*) (ws + WREG + 851968);        // 262144 B fp8
    uchar_t*  whhb8  = (uchar_t*) (ws + WREG + 917504);        // 262144 B fp8
    ushort_t* embw   = (ushort_t*)(ws + WREG + 1114112);
    ushort_t* cwL    = (ushort_t*)(ws + WREG + 1179648);
    uchar_t*  cwR8   = (uchar_t*) (ws + WREG + 1212416);       // 65536 B fp8
    uchar_t*  gwih8  = (uchar_t*) (ws + WREG + 1245184);       // 196608 B fp8
    uchar_t*  gwhh8  = (uchar_t*) (ws + WREG + 1294336);       // 196608 B fp8
    ushort_t* outw   = (ushort_t*)(ws + WREG + 1343488);
    float*    outb   = ws + WREG + 1359872;
    float*    bias2f = ws + WREG + 1360000;                    // [bias2f|bias2b] stacked
    float*    bias2b = ws + WREG + 1361024;

    dim3 blk(256);

    convert_all_k<<<11402, blk, 0, stream>>>(
        conv1_w, conv2_w, wih_f, wih_b, whh_f, whh_b, emb_w, comb_w,
        gru_wih, gru_whh, out_w, out_b, bih_f, bhh_f, bih_b, bhh_b,
        c1w, c2w, wihf, (ushort_t*)(ws + WREG + 720896), whhf8, whhb8, embw,
        cwL, cwR8, gwih8, gwhh8, outw, outb, bias2f, bias2b);

    // ---- encoder: conv1+GN1 fused, conv2+GN2+pool+transpose fused ----
    nchw2nhwc_k<<<16384, blk, 0, stream>>>(rois, R);
    convf_k<0><<<dim3(1, 512), blk, 0, stream>>>(R, c1w, gn1_s, gn1_b, X1b, 8, 3, 7);
    convf_k<1><<<dim3(1, 256), blk, 0, stream>>>(X1b, c2w, gn2_s, gn2_b, xT, 4, 1, 6);

    // ---- merged LSTM input gates: xg = xT @ [wihf;wihb]^T + [b2f;b2b] ----
    mgemm_k<1,0><<<dim3(16, 128), blk, 0, stream>>>(xT, wihf, bias2f, xg, 16384, 2048, 256);

    // ---- persistent bidirectional LSTM (256 blocks, fp8 weights in regs) ----
    lstm_persist_k<<<256, dim3(512), 0, stream>>>(xg, whhf8, whhb8, hcat);

    // enc = hcat @ emb_w^T + emb_b  (bf16 out)
    mgemm_k<1,0><<<dim3(2, 128), blk, 0, stream>>>(hcat, embw, emb_b, enc, 16384, 256, 512);

    // ---- decoder precompute: EMB gather + xinpre = EMB@cwL^T + comb_b (bf16) ----
    emb_gather_k<<<12800, blk, 0, stream>>>(targets, att_emb, EMB);
    mgemm_k<1,0><<<dim3(2, 100), blk, 0, stream>>>(EMB, cwL, comb_b, xinpre, 12800, 256, 256);

    // ---- block-local attention-GRU decoder (proven v9: 256 blk x 2 rois) ----
    dec_local_k<<<256, dim3(512), 0, stream>>>(enc, xinpre, cwR8, gwih8, gwhh8,
        gru_bih, gru_bhh, vat_w, vat_b, hist);

    // ---- deferred output projection + loss ----
    mgemm_k<0,0><<<dim3(1, 100), blk, 0, stream>>>(hist, outw, outb, logitsA, 12800, 128, 256);
    loss_batch_k<<<TDEC, blk, 0, stream>>>(logitsA, targets, lpart);
    loss_final_k<<<1, dim3(64), 0, stream>>>(lpart, (float*)d_out);
}